// Round 1
// 229.419 us; speedup vs baseline: 1.0389x; 1.0389x over previous
//
#include <hip/hip_runtime.h>
#include <hip/hip_bf16.h>

// Problem constants
#define BATCH   4096
#define HIDDEN  128
#define SESS    50
#define KTOT    4096
#define NB      ((size_t)BATCH * HIDDEN)   // 524288 elems per (B,H) buffer

typedef __bf16 bf16x8 __attribute__((ext_vector_type(8)));
typedef float  f32x4  __attribute__((ext_vector_type(4)));
typedef float  f32x2  __attribute__((ext_vector_type(2)));

__device__ __forceinline__ f32x4 mfma_bf16(bf16x8 a, bf16x8 b, f32x4 c) {
    return __builtin_amdgcn_mfma_f32_16x16x32_bf16(a, b, c, 0, 0, 0);
}

// Async global->LDS, 16B per lane. Dest is wave-uniform base + lane*16 (linear);
// source is per-lane. Completion tracked by vmcnt.
__device__ __forceinline__ void gload16(const void* g, void* l) {
    __builtin_amdgcn_global_load_lds(
        (const __attribute__((address_space(1))) void*)g,
        (__attribute__((address_space(3))) void*)l, 16, 0, 0);
}

// Packed B-operand layout: elem(k, h) -> (k>>3)*1024 + (h>>4)*128 + (h&15)*8 + (k&7)
// A wave's 32-k chunk = 4096 contiguous elems = 8 KB -> linear global_load_lds.
// In-chunk fragment (quad, nt, lo): byte = quad*2048 + nt*256 + lo*16 (ds_read_b128,
// conflict-free: 8-lane groups span all 32 banks).

// ---------------------------------------------------------------------------
// Gather: E[b][h] = sum_s emb[items[b][s]][h], written ONLY as packed bf16.
// One wave per output row: lane = (h half, c chunk); 25 independent f32x4
// loads per lane, one __shfl_xor(32) combine, no LDS reduce tree.
// ---------------------------------------------------------------------------
__global__ __launch_bounds__(256)
void gather_sum_kernel(const float* __restrict__ emb,
                       const int* __restrict__ items32,
                       __bf16* __restrict__ ETp) {
    __shared__ int sidx[4][SESS];
    const int t  = threadIdx.x;
    const int b0 = blockIdx.x * 4;
    const bool is64 = (items32[1] | items32[3] | items32[5] | items32[7] |
                       items32[9] | items32[11] | items32[13] | items32[15]) == 0;
    if (t < 4 * SESS) {
        const int w_ = t / SESS, s_ = t % SESS;
        sidx[w_][s_] = is64
            ? (int)((const long long*)items32)[(long)(b0 + w_) * SESS + s_]
            : items32[(b0 + w_) * SESS + s_];
    }
    __syncthreads();
    const int w    = t >> 6;
    const int lane = t & 63;
    const int c    = lane & 31;   // f32x4 chunk within the 128-wide row
    const int h    = lane >> 5;   // session-parity half
    f32x4 acc = {0.f, 0.f, 0.f, 0.f};
#pragma unroll
    for (int i = 0; i < 25; ++i) {
        acc += *(const f32x4*)(emb + (long)sidx[w][h + 2 * i] * HIDDEN + c * 4);
    }
#pragma unroll
    for (int j = 0; j < 4; ++j) acc[j] += __shfl_xor(acc[j], 32, 64);
    if (h == 0) {
        const int b  = b0 + w;
        const int h0 = c * 4;
        const long pb = ((long)(b >> 3) << 10) + (b & 7) + ((h0 >> 4) << 7);
#pragma unroll
        for (int j = 0; j < 4; ++j)
            ETp[pb + ((h0 & 15) + j) * 8] = (__bf16)acc[j];
    }
}

// ---------------------------------------------------------------------------
// MFMA GEMM v3: partial_sy = X[:, sy*1024:(sy+1)*1024] @ B   (X fp32, B packed bf16)
// grid (256,4) x 256 thr. 4 waves split the 1024-k superslice (256 k each).
// B staged per-wave through a 2-chunk LDS ring via global_load_lds (zero VGPR
// cost, deep async queue), counted s_waitcnt vmcnt(10) -- never drained to 0
// in the loop. A kept in a 2-deep register prefetch (16 VGPRs). No barriers
// in the K-loop (each wave reads only its own LDS). Hardcoded C/D layout:
// row = quad*4 + reg, col = lane&15  [HW-verified MI355X, learn_hip m89/m91].
// LDS 64 KB: 4 waves x (2 x 8 KB ring); epilogue reduce overlays it.
// ---------------------------------------------------------------------------
__global__ __launch_bounds__(256, 2)
void gemm_mfma_kernel(const float* __restrict__ X,
                      const __bf16* __restrict__ Bpk,
                      float* __restrict__ Tp) {
    __shared__ __align__(16) float raw[16384];   // 64 KB
    const int tid  = threadIdx.x;
    const int wave = tid >> 6;
    const int lane = tid & 63;
    const int lo   = lane & 15;
    const int quad = lane >> 4;
    const int rowBase = blockIdx.x * 16;
    const int sy      = blockIdx.y;
    const int kBase   = sy * 1024 + wave * 256;

    const float* apt   = X + (long)(rowBase + lo) * KTOT + kBase + quad * 8;
    const char*  bsrc  = (const char*)Bpk + ((long)(kBase >> 3) << 11);
    char*        sbase = (char*)raw + wave * 16384;

    f32x4 acc[8];
#pragma unroll
    for (int i = 0; i < 8; ++i) acc[i] = (f32x4){0.f, 0.f, 0.f, 0.f};

    f32x4 xa0[2], xa1[2];

#define STAGE(ks_, cur_) do {                                                \
    const char* g_ = bsrc + (ks_) * 8192 + lane * 16;                        \
    char* l_ = sbase + (cur_) * 8192;                                        \
    _Pragma("unroll")                                                        \
    for (int i_ = 0; i_ < 8; ++i_)                                           \
        gload16(g_ + i_ * 1024, l_ + i_ * 1024);                             \
} while (0)

    // prologue: per slot, A-regs (2 vmem) then B-chunk stage (8 vmem) = 10 ops
    xa0[0] = *(const f32x4*)(apt);
    xa1[0] = *(const f32x4*)(apt + 4);
    STAGE(0, 0);
    xa0[1] = *(const f32x4*)(apt + 32);
    xa1[1] = *(const f32x4*)(apt + 36);
    STAGE(1, 1);

    // Per iter: vmcnt(10) leaves the next slot's 10 vmem ops in flight.
    // ds_reads -> a-frag cvt -> lgkmcnt(0)+sched_barrier (WAR guard before
    // restaging into the just-read buffer; also pins MFMAs below, rule 18)
    // -> issue next-next slot -> 8 MFMAs.
#define GITER(ks_, cur_, WAIT_, PRE_) do {                                   \
    asm volatile(WAIT_ ::: "memory");                                        \
    bf16x8 bb[8];                                                            \
    _Pragma("unroll")                                                        \
    for (int nt_ = 0; nt_ < 8; ++nt_)                                        \
        bb[nt_] = *(const bf16x8*)(sbase + (cur_) * 8192 + quad * 2048 +     \
                                   nt_ * 256 + lo * 16);                     \
    bf16x8 a;                                                                \
    a[0] = (__bf16)xa0[cur_][0]; a[1] = (__bf16)xa0[cur_][1];                \
    a[2] = (__bf16)xa0[cur_][2]; a[3] = (__bf16)xa0[cur_][3];                \
    a[4] = (__bf16)xa1[cur_][0]; a[5] = (__bf16)xa1[cur_][1];                \
    a[6] = (__bf16)xa1[cur_][2]; a[7] = (__bf16)xa1[cur_][3];                \
    asm volatile("s_waitcnt lgkmcnt(0)" ::: "memory");                       \
    __builtin_amdgcn_sched_barrier(0);                                       \
    if (PRE_) {                                                              \
        xa0[cur_] = *(const f32x4*)(apt + ((ks_) + 2) * 32);                 \
        xa1[cur_] = *(const f32x4*)(apt + ((ks_) + 2) * 32 + 4);             \
        STAGE((ks_) + 2, cur_);                                              \
    }                                                                        \
    _Pragma("unroll")                                                        \
    for (int nt_ = 0; nt_ < 8; ++nt_)                                        \
        acc[nt_] = mfma_bf16(a, bb[nt_], acc[nt_]);                          \
} while (0)

    GITER(0, 0, "s_waitcnt vmcnt(10)", 1);
    GITER(1, 1, "s_waitcnt vmcnt(10)", 1);
    GITER(2, 0, "s_waitcnt vmcnt(10)", 1);
    GITER(3, 1, "s_waitcnt vmcnt(10)", 1);
    GITER(4, 0, "s_waitcnt vmcnt(10)", 1);
    GITER(5, 1, "s_waitcnt vmcnt(10)", 1);
    GITER(6, 0, "s_waitcnt vmcnt(10)", 0);
    GITER(7, 1, "s_waitcnt vmcnt(0)",  0);

#undef GITER
#undef STAGE

    // Cross-wave reduce: overlay staging LDS (all waves drained own vmcnt(0)).
    __syncthreads();
    float (*red)[16][132] = (float (*)[16][132])raw;   // +4 pad: bank spread
#pragma unroll
    for (int r = 0; r < 4; ++r) {
        const int dr = quad * 4 + r;                    // C/D row (m89/m91)
#pragma unroll
        for (int nt = 0; nt < 8; ++nt)
            red[wave][dr][nt * 16 + lo] = acc[nt][r];   // col = lo
    }
    __syncthreads();
    const int row = tid >> 4;
    const int cb  = (tid & 15) * 8;
    f32x4 v0 = {0.f, 0.f, 0.f, 0.f}, v1 = {0.f, 0.f, 0.f, 0.f};
#pragma unroll
    for (int w = 0; w < 4; ++w) {
        v0 += *(const f32x4*)&red[w][row][cb];
        v1 += *(const f32x4*)&red[w][row][cb + 4];
    }
    float* outp = Tp + (size_t)sy * NB + (long)(rowBase + row) * HIDDEN + cb;
    *(f32x4*)(outp)     = v0;
    *(f32x4*)(outp + 4) = v1;
}

// ---------------------------------------------------------------------------
// reduce4: TTp(packed bf16) = sum of 4 fp32 k-slice partials. (fp32 write-back
// dropped -- it only fed the deleted fallback path.)
// ---------------------------------------------------------------------------
__global__ __launch_bounds__(256)
void reduce4_kernel(const float* __restrict__ Tp, __bf16* __restrict__ TTp) {
    const size_t i = ((size_t)blockIdx.x * 256 + threadIdx.x) * 4;
    f32x4 a = *(const f32x4*)(Tp + i);
    a += *(const f32x4*)(Tp + NB + i);
    a += *(const f32x4*)(Tp + 2 * NB + i);
    a += *(const f32x4*)(Tp + 3 * NB + i);
    const int b  = (int)(i >> 7);
    const int h0 = (int)(i & 127);
    const long pb = ((long)(b >> 3) << 10) + (b & 7) + ((h0 >> 4) << 7);
#pragma unroll
    for (int j = 0; j < 4; ++j)
        TTp[pb + ((h0 & 15) + j) * 8] = (__bf16)a[j];
}

// ---------------------------------------------------------------------------
// reduce_norm: out[row] = normalize(sum of 4 fp32 partials). One wave per row,
// 2 floats/lane, 6-step __shfl_xor reduce -- no LDS, no barriers.
// ---------------------------------------------------------------------------
__global__ __launch_bounds__(256)
void reduce_norm_kernel(const float* __restrict__ Tp, float* __restrict__ out) {
    const int t    = threadIdx.x;
    const int w    = t >> 6;
    const int lane = t & 63;
    const int row  = blockIdx.x * 4 + w;
    const size_t base = (size_t)row * HIDDEN + lane * 2;
    f32x2 v = *(const f32x2*)(Tp + base);
    v += *(const f32x2*)(Tp + NB + base);
    v += *(const f32x2*)(Tp + 2 * NB + base);
    v += *(const f32x2*)(Tp + 3 * NB + base);
    float sq = v[0] * v[0] + v[1] * v[1];
#pragma unroll
    for (int m = 1; m < 64; m <<= 1) sq += __shfl_xor(sq, m, 64);
    const float s = rsqrtf(sq);
    f32x2 o = {v[0] * s, v[1] * s};
    *(f32x2*)(out + base) = o;
}

// ---------------------------------------------------------------------------
// out = normalize_rows( D @ (A @ E) )   [associativity: 137 GF -> 8.6 GF]
// 5 dispatches (was 9): probe + fp32 fallbacks removed (layout hardcoded per
// HW-verified m89/m91 mapping; harness absmax check is the guard).
// ws: ETp bf16 1MB | TTp bf16 1MB | Tp fp32 x4 8MB  (~10 MB)
// ---------------------------------------------------------------------------
extern "C" void kernel_launch(void* const* d_in, const int* in_sizes, int n_in,
                              void* d_out, int out_size, void* d_ws, size_t ws_size,
                              hipStream_t stream) {
    const float* emb   = (const float*)d_in[0];
    const int*   items = (const int*)d_in[1];
    const float* A     = (const float*)d_in[2];
    const float* D     = (const float*)d_in[3];
    float* out = (float*)d_out;

    __bf16* ETp = (__bf16*)d_ws;
    __bf16* TTp = ETp + NB;
    float*  Tp  = (float*)(TTp + NB);

    gather_sum_kernel<<<BATCH / 4, 256, 0, stream>>>(emb, items, ETp);

    // Phase 1: T = A @ E (4 k-slice partials -> reduce to packed bf16)
    gemm_mfma_kernel<<<dim3(BATCH / 16, 4), 256, 0, stream>>>(A, ETp, Tp);
    reduce4_kernel<<<512, 256, 0, stream>>>(Tp, TTp);

    // Phase 2: R = D @ T (partials), then fused reduce + row-normalize
    gemm_mfma_kernel<<<dim3(BATCH / 16, 4), 256, 0, stream>>>(D, TTp, Tp);
    reduce_norm_kernel<<<BATCH / 4, 256, 0, stream>>>(Tp, out);
}

// Round 2
// 226.996 us; speedup vs baseline: 1.0500x; 1.0107x over previous
//
#include <hip/hip_runtime.h>
#include <hip/hip_bf16.h>

// Problem constants
#define BATCH   4096
#define HIDDEN  128
#define SESS    50
#define KTOT    4096
#define NB      ((size_t)BATCH * HIDDEN)

// GEMM tiling
#define BK        512                 // k per LDS tile
#define KCH       16                  // 32-k MFMA steps per tile
#define NTILES    (KTOT / BK)         // 8
#define ROWSTRIDE 2064                // bytes per A-row in LDS (2048 + 16 pad -> 2-way alias, free)
#define BUFSZ     (16 * ROWSTRIDE)    // 33024 B per buffer

typedef __bf16 bf16x8 __attribute__((ext_vector_type(8)));
typedef __bf16 bf16x4 __attribute__((ext_vector_type(4)));
typedef float  f32x4  __attribute__((ext_vector_type(4)));

__device__ __forceinline__ f32x4 mfma_bf16(bf16x8 a, bf16x8 b, f32x4 c) {
    return __builtin_amdgcn_mfma_f32_16x16x32_bf16(a, b, c, 0, 0, 0);
}

// Async global->LDS, 16B/lane. LDS dest = wave-uniform base + lane*16 (linear);
// global src is per-lane. Tracked by vmcnt.
__device__ __forceinline__ void gload16(const void* g, void* l) {
    __builtin_amdgcn_global_load_lds(
        (const __attribute__((address_space(1))) void*)g,
        (__attribute__((address_space(3))) void*)l, 16, 0, 0);
}

// Packed B layout: elem(k,h) -> (k>>3)*1024 + (h>>4)*128 + (h&15)*8 + (k&7)

// ---------------------------------------------------------------------------
// Gather: E[b][h] = sum_s emb[items[b][s]][h] -> packed bf16 ETp.
// One wave per row; 25 independent f32x4 loads/lane; one shfl combine.
// ---------------------------------------------------------------------------
__global__ __launch_bounds__(256)
void gather_sum_kernel(const float* __restrict__ emb,
                       const int* __restrict__ items32,
                       __bf16* __restrict__ ETp) {
    __shared__ int sidx[4][SESS];
    const int t  = threadIdx.x;
    const int b0 = blockIdx.x * 4;
    const bool is64 = (items32[1] | items32[3] | items32[5] | items32[7] |
                       items32[9] | items32[11] | items32[13] | items32[15]) == 0;
    if (t < 4 * SESS) {
        const int w_ = t / SESS, s_ = t % SESS;
        sidx[w_][s_] = is64
            ? (int)((const long long*)items32)[(long)(b0 + w_) * SESS + s_]
            : items32[(b0 + w_) * SESS + s_];
    }
    __syncthreads();
    const int w    = t >> 6;
    const int lane = t & 63;
    const int c    = lane & 31;
    const int h    = lane >> 5;
    f32x4 acc = {0.f, 0.f, 0.f, 0.f};
#pragma unroll
    for (int i = 0; i < 25; ++i) {
        acc += *(const f32x4*)(emb + (long)sidx[w][h + 2 * i] * HIDDEN + c * 4);
    }
#pragma unroll
    for (int j = 0; j < 4; ++j) acc[j] += __shfl_xor(acc[j], 32, 64);
    if (h == 0) {
        const int b  = b0 + w;
        const int h0 = c * 4;
        const long pb = ((long)(b >> 3) << 10) + (b & 7) + ((h0 >> 4) << 7);
#pragma unroll
        for (int j = 0; j < 4; ++j)
            ETp[pb + ((h0 & 15) + j) * 8] = (__bf16)acc[j];
    }
}

// ---------------------------------------------------------------------------
// GEMM v4 (DRAM-friendly A): C[16 x 128] = X[16 x 4096] @ Bpk[4096 x 128].
// grid 256 blocks (1/CU), 256 thr. All 4 waves share a double-buffered LDS
// A-tile [16][512] fp32 staged by whole-row 1KB global_load_lds ops (2KB
// sequential per row per tile -> DRAM row-hit friendly). Counted vmcnt(8) +
// raw s_barrier (m201 discipline), stage of tile t+1 in flight across tile
// t's compute. Wave w owns n-tiles {2w, 2w+1} for the FULL K -> private
// accumulators, no cross-wave reduce.
// PHASE 1: store packed-bf16 TTp straight from accs (4 r-values are 4
//          consecutive packed bytes*2: addr = (rowBase>>3 + (quad>>1))*1024
//          + nt*128 + lo*8 + (quad&1)*4 + r).
// PHASE 2: fused row L2-normalize via small LDS tile + 16-lane shfl reduce.
// C/D layout: row = quad*4 + reg, col = lane&15  [HW-verified m89/m91].
// ---------------------------------------------------------------------------
template <int PHASE>
__global__ __launch_bounds__(256, 1)
void gemm_mfma_kernel(const float* __restrict__ X,
                      const __bf16* __restrict__ Bpk,
                      __bf16* __restrict__ TTp,
                      float* __restrict__ out) {
    __shared__ __align__(16) char lds[2 * BUFSZ];   // 66048 B
    const int tid  = threadIdx.x;
    const int w    = tid >> 6;
    const int lane = tid & 63;
    const int lo   = lane & 15;
    const int quad = lane >> 4;
    const int rowBase = blockIdx.x * 16;

    // wave w stages rows 4w..4w+3, pieces 0..1 (1 KB each) of each tile
    const float* xb = X + (size_t)(rowBase + 4 * w) * KTOT + lane * 4;

#define STAGE(t_, b_) do {                                                   \
    _Pragma("unroll")                                                        \
    for (int r_ = 0; r_ < 4; ++r_) {                                         \
        _Pragma("unroll")                                                    \
        for (int p_ = 0; p_ < 2; ++p_) {                                     \
            gload16(xb + (size_t)r_ * KTOT + (t_) * BK + p_ * 256,           \
                    lds + (b_) * BUFSZ + (4 * w + r_) * ROWSTRIDE +          \
                        p_ * 1024);                                          \
        }                                                                    \
    }                                                                        \
} while (0)

    f32x4 acc0 = {0.f, 0.f, 0.f, 0.f};
    f32x4 acc1 = {0.f, 0.f, 0.f, 0.f};
    // B frag base for this wave: n-tiles 2w, 2w+1
    const __bf16* bq = Bpk + quad * 1024 + (2 * w) * 128 + lo * 8;

#define KTILE(t_, cur_) do {                                                 \
    const char* As = lds + (cur_) * BUFSZ + lo * ROWSTRIDE + quad * 32;      \
    const __bf16* bp = bq + (size_t)(t_) * KCH * 4096;                       \
    _Pragma("unroll")                                                        \
    for (int ks = 0; ks < KCH; ++ks) {                                       \
        const f32x4 a0 = *(const f32x4*)(As + ks * 128);                     \
        const f32x4 a1 = *(const f32x4*)(As + ks * 128 + 16);                \
        const bf16x8 b0 = *(const bf16x8*)(bp + (size_t)ks * 4096);          \
        const bf16x8 b1 = *(const bf16x8*)(bp + (size_t)ks * 4096 + 128);    \
        bf16x8 af;                                                           \
        af[0] = (__bf16)a0[0]; af[1] = (__bf16)a0[1];                        \
        af[2] = (__bf16)a0[2]; af[3] = (__bf16)a0[3];                        \
        af[4] = (__bf16)a1[0]; af[5] = (__bf16)a1[1];                        \
        af[6] = (__bf16)a1[2]; af[7] = (__bf16)a1[3];                        \
        acc0 = mfma_bf16(af, b0, acc0);                                      \
        acc1 = mfma_bf16(af, b1, acc1);                                      \
    }                                                                        \
} while (0)

    STAGE(0, 0);
    for (int t = 0; t < NTILES - 1; ++t) {
        const int cur = t & 1;
        STAGE(t + 1, cur ^ 1);                              // 8 async ops out
        asm volatile("s_waitcnt vmcnt(8)" ::: "memory");    // own tile-t done
        __builtin_amdgcn_s_barrier();                       // all waves' rows
        __builtin_amdgcn_sched_barrier(0);
        KTILE(t, cur);
        __builtin_amdgcn_s_barrier();                       // reads done before
        __builtin_amdgcn_sched_barrier(0);                  // t+2 overwrites
    }
    {   // last tile
        asm volatile("s_waitcnt vmcnt(0)" ::: "memory");
        __builtin_amdgcn_s_barrier();
        __builtin_amdgcn_sched_barrier(0);
        KTILE(NTILES - 1, (NTILES - 1) & 1);
        __builtin_amdgcn_s_barrier();
        __builtin_amdgcn_sched_barrier(0);
    }
#undef KTILE
#undef STAGE

    if (PHASE == 1) {
        // Direct packed-bf16 store: per nt, the 4 acc regs are 4 consecutive
        // packed elems (b&7 = (quad&1)*4 + r).
        __bf16* tb = TTp + ((rowBase >> 3) + (quad >> 1)) * 1024 + lo * 8 +
                     (quad & 1) * 4;
        bf16x4 p0, p1;
#pragma unroll
        for (int r = 0; r < 4; ++r) {
            p0[r] = (__bf16)acc0[r];
            p1[r] = (__bf16)acc1[r];
        }
        *(bf16x4*)(tb + (2 * w) * 128)     = p0;
        *(bf16x4*)(tb + (2 * w + 1) * 128) = p1;
    } else {
        // Fused row-normalize. Reuse LDS (last barrier above guarantees all
        // tile reads finished).
        float (*Cs)[136] = (float (*)[136])lds;   // pad 136: f32x4-aligned rows
#pragma unroll
        for (int r = 0; r < 4; ++r) {
            Cs[quad * 4 + r][(2 * w) * 16 + lo]     = acc0[r];
            Cs[quad * 4 + r][(2 * w + 1) * 16 + lo] = acc1[r];
        }
        __syncthreads();
        const int row = tid >> 4;
        const int cg  = tid & 15;
        const f32x4 c0 = *(const f32x4*)&Cs[row][cg * 8];
        const f32x4 c1 = *(const f32x4*)&Cs[row][cg * 8 + 4];
        float sq = c0[0] * c0[0] + c0[1] * c0[1] + c0[2] * c0[2] +
                   c0[3] * c0[3] + c1[0] * c1[0] + c1[1] * c1[1] +
                   c1[2] * c1[2] + c1[3] * c1[3];
#pragma unroll
        for (int m = 1; m < 16; m <<= 1) sq += __shfl_xor(sq, m, 64);
        const float s = rsqrtf(sq);
        float* op = out + (size_t)(rowBase + row) * HIDDEN + cg * 8;
        f32x4 o0, o1;
#pragma unroll
        for (int j = 0; j < 4; ++j) { o0[j] = c0[j] * s; o1[j] = c1[j] * s; }
        *(f32x4*)(op)     = o0;
        *(f32x4*)(op + 4) = o1;
    }
}

// ---------------------------------------------------------------------------
// out = normalize_rows( D @ (A @ E) )
// 3 dispatches: gather -> gemm<1> (writes packed TTp directly) -> gemm<2>
// (fused normalize). ws: ETp 1MB | TTp 1MB.
// ---------------------------------------------------------------------------
extern "C" void kernel_launch(void* const* d_in, const int* in_sizes, int n_in,
                              void* d_out, int out_size, void* d_ws, size_t ws_size,
                              hipStream_t stream) {
    const float* emb   = (const float*)d_in[0];
    const int*   items = (const int*)d_in[1];
    const float* A     = (const float*)d_in[2];
    const float* D     = (const float*)d_in[3];
    float* out = (float*)d_out;

    __bf16* ETp = (__bf16*)d_ws;
    __bf16* TTp = ETp + NB;

    gather_sum_kernel<<<BATCH / 4, 256, 0, stream>>>(emb, items, ETp);
    gemm_mfma_kernel<1><<<BATCH / 16, 256, 0, stream>>>(A, ETp, TTp, nullptr);
    gemm_mfma_kernel<2><<<BATCH / 16, 256, 0, stream>>>(D, TTp, nullptr, out);
}

// Round 3
// 207.428 us; speedup vs baseline: 1.1491x; 1.0943x over previous
//
#include <hip/hip_runtime.h>
#include <hip/hip_bf16.h>

// Problem constants
#define BATCH   4096
#define HIDDEN  128
#define SESS    50
#define KTOT    4096
#define NB      ((size_t)BATCH * HIDDEN)

// GEMM tiling: block = 16 rows x 128 cols x full K; BK=128 per LDS tile.
#define BK      128
#define NTILES  (KTOT / BK)          // 32
#define ABYTES  8192                 // 16 rows * 128 k * 4B
#define BBYTES  32768                // 128 k * 128 cols * 2B
#define BUF     (ABYTES + BBYTES)    // 40960; x3 buffers = 122880 B LDS

typedef __bf16 bf16x8 __attribute__((ext_vector_type(8)));
typedef __bf16 bf16x4 __attribute__((ext_vector_type(4)));
typedef float  f32x4  __attribute__((ext_vector_type(4)));

__device__ __forceinline__ f32x4 mfma_bf16(bf16x8 a, bf16x8 b, f32x4 c) {
    return __builtin_amdgcn_mfma_f32_16x16x32_bf16(a, b, c, 0, 0, 0);
}

// Async global->LDS, 16B/lane. LDS dest = wave-uniform base (+lane*16 by HW);
// global src is per-lane (swizzles live on the source side). Tracked by vmcnt.
__device__ __forceinline__ void gload16(const void* g, void* l) {
    __builtin_amdgcn_global_load_lds(
        (const __attribute__((address_space(1))) void*)g,
        (__attribute__((address_space(3))) void*)l, 16, 0, 0);
}

// Packed B layout (BYTES), XOR-swizzled for conflict-free ds_read_b128:
//   elem(k,h) -> (k>>3)*2048 + [ (h>>4)*256 + (h&15)*16 + (k&7)*2 ] ^ (((k>>3)&3)<<4)
// K-loop read (tile-local chunk c = ks*4+quad, so c&3 == quad):
//   byte = c*2048 + ((nt*256 + lo*16) ^ (quad<<4))  -> granule (lo^quad)&7: even spread.
// A-tile LDS layout: [row][512B] linear rows; within-row byte w holds global
// byte (w ^ ((row&7)<<4)) -> ds_read granule ((base>>4) ^ (lo&7)): even spread.

// ---------------------------------------------------------------------------
// Gather: E[b][h] = sum_s emb[items[b][s]][h] -> packed bf16 ETp (layout above).
// ---------------------------------------------------------------------------
__global__ __launch_bounds__(256)
void gather_sum_kernel(const float* __restrict__ emb,
                       const int* __restrict__ items32,
                       __bf16* __restrict__ ETp) {
    __shared__ int sidx[4][SESS];
    const int t  = threadIdx.x;
    const int b0 = blockIdx.x * 4;
    const bool is64 = (items32[1] | items32[3] | items32[5] | items32[7] |
                       items32[9] | items32[11] | items32[13] | items32[15]) == 0;
    if (t < 4 * SESS) {
        const int w_ = t / SESS, s_ = t % SESS;
        sidx[w_][s_] = is64
            ? (int)((const long long*)items32)[(long)(b0 + w_) * SESS + s_]
            : items32[(b0 + w_) * SESS + s_];
    }
    __syncthreads();
    const int w    = t >> 6;
    const int lane = t & 63;
    const int c    = lane & 31;
    const int h    = lane >> 5;
    f32x4 acc = {0.f, 0.f, 0.f, 0.f};
#pragma unroll
    for (int i = 0; i < 25; ++i) {
        acc += *(const f32x4*)(emb + (long)sidx[w][h + 2 * i] * HIDDEN + c * 4);
    }
#pragma unroll
    for (int j = 0; j < 4; ++j) acc[j] += __shfl_xor(acc[j], 32, 64);
    if (h == 0) {
        const int  b     = b0 + w;
        const long chunk = b >> 3;
        const int  swz   = (int)((chunk & 3) << 4);
        char* basep = (char*)ETp + chunk * 2048 + (b & 7) * 2;
        const int hi4 = (c >> 2) * 256;          // (h>>4)*256
#pragma unroll
        for (int j = 0; j < 4; ++j) {
            const int hl = 4 * (c & 3) + j;      // h&15
            *(__bf16*)(basep + ((hi4 + hl * 16) ^ swz)) = (__bf16)acc[j];
        }
    }
}

// ---------------------------------------------------------------------------
// GEMM v5 (pure-LDS K-loop): C[16x128] = X[16x4096] @ Bpk[4096x128].
// grid 256 x 256thr (4 waves). Per BK=128 tile both operands staged to LDS by
// global_load_lds (10 ops/wave: 2 A + 8 B), triple-buffered, prefetch depth 2,
// counted vmcnt(20/10/0), raw s_barrier (no drain in loop). K-loop is
// ds_read + cvt + MFMA only -- zero global loads, compiler-managed lgkmcnt.
// Wave w owns n-tiles {2w,2w+1} full-K: private accs, no cross-wave reduce.
// C/D layout: row = quad*4 + reg, col = lane&15 [HW-verified m89/m91].
// PHASE 1: direct packed-bf16 store of T. PHASE 2: fused row L2-normalize.
// ---------------------------------------------------------------------------
template <int PHASE>
__global__ __launch_bounds__(256, 1)
void gemm_mfma_kernel(const float* __restrict__ X,
                      const __bf16* __restrict__ Bpk,
                      __bf16* __restrict__ TTp,
                      float* __restrict__ out) {
    __shared__ __align__(16) char lds[3 * BUF];   // 122880 B
    const int tid  = threadIdx.x;
    const int w    = tid >> 6;
    const int lane = tid & 63;
    const int lo   = lane & 15;
    const int quad = lane >> 4;
    const int rowBase = blockIdx.x * 16;

    // ---- staging: wave w -> A ops {2w,2w+1} (2 rows each), B ops {8w..8w+7}
#define STAGE(t_, dst_) do {                                                 \
    _Pragma("unroll")                                                        \
    for (int oi_ = 0; oi_ < 2; ++oi_) {                                      \
        const int o_    = 2 * w + oi_;                                       \
        const int rloc_ = 2 * o_ + (lane >> 5);                              \
        gload16((const char*)X +                                             \
                    ((size_t)(rowBase + rloc_) * KTOT + (size_t)(t_) * BK) * 4 + \
                    (((lane & 31) * 16) ^ ((rloc_ & 7) << 4)),               \
                (dst_) + o_ * 1024);                                         \
    }                                                                        \
    _Pragma("unroll")                                                        \
    for (int bi_ = 0; bi_ < 8; ++bi_) {                                      \
        const int i_ = 8 * w + bi_;                                          \
        gload16((const char*)Bpk + (size_t)(t_) * BBYTES + i_ * 1024 +       \
                    lane * 16,                                               \
                (dst_) + ABYTES + i_ * 1024);                                \
    }                                                                        \
} while (0)

    f32x4 acc0 = {0.f, 0.f, 0.f, 0.f};
    f32x4 acc1 = {0.f, 0.f, 0.f, 0.f};

    const int akey = (lo & 7) << 4;
    const int bswz = quad << 4;
    const int bc0  = (int)(((2 * w) * 256 + lo * 16) ^ bswz);
    const int bc1  = (int)(((2 * w + 1) * 256 + lo * 16) ^ bswz);

#define KTILE(cb_) do {                                                      \
    const char* Ar_ = (cb_) + lo * 512;                                      \
    const char* Bb_ = (cb_) + ABYTES + quad * 2048;                          \
    _Pragma("unroll")                                                        \
    for (int ks_ = 0; ks_ < 4; ++ks_) {                                      \
        const f32x4 a0_ =                                                    \
            *(const f32x4*)(Ar_ + ((ks_ * 128 + quad * 32) ^ akey));         \
        const f32x4 a1_ =                                                    \
            *(const f32x4*)(Ar_ + ((ks_ * 128 + quad * 32 + 16) ^ akey));    \
        const bf16x8 b0_ = *(const bf16x8*)(Bb_ + ks_ * 8192 + bc0);         \
        const bf16x8 b1_ = *(const bf16x8*)(Bb_ + ks_ * 8192 + bc1);         \
        bf16x8 af_;                                                          \
        af_[0] = (__bf16)a0_[0]; af_[1] = (__bf16)a0_[1];                    \
        af_[2] = (__bf16)a0_[2]; af_[3] = (__bf16)a0_[3];                    \
        af_[4] = (__bf16)a1_[0]; af_[5] = (__bf16)a1_[1];                    \
        af_[6] = (__bf16)a1_[2]; af_[7] = (__bf16)a1_[3];                    \
        acc0 = mfma_bf16(af_, b0_, acc0);                                    \
        acc1 = mfma_bf16(af_, b1_, acc1);                                    \
    }                                                                        \
} while (0)

    // prologue: tiles 0,1 in flight (20 vmem ops/wave)
    STAGE(0, lds);
    STAGE(1, lds + BUF);

    char* cb = lds;               // compute buffer (tile t   -> t%3)
    char* sb = lds + 2 * BUF;     // stage buffer   (tile t+2 -> (t+2)%3)
    for (int t = 0; t < NTILES; ++t) {
        if (t + 2 < NTILES) STAGE(t + 2, sb);
        if (t < NTILES - 2)
            asm volatile("s_waitcnt vmcnt(20)" ::: "memory");
        else if (t == NTILES - 2)
            asm volatile("s_waitcnt vmcnt(10)" ::: "memory");
        else
            asm volatile("s_waitcnt vmcnt(0)" ::: "memory");
        __builtin_amdgcn_s_barrier();        // all waves' tile-t staging done
        __builtin_amdgcn_sched_barrier(0);
        KTILE(cb);
        __builtin_amdgcn_s_barrier();        // reads done before t+3 restages
        __builtin_amdgcn_sched_barrier(0);
        cb += BUF; if (cb == lds + 3 * BUF) cb = lds;
        sb += BUF; if (sb == lds + 3 * BUF) sb = lds;
    }
#undef KTILE
#undef STAGE

    if (PHASE == 1) {
        // Direct packed-bf16 store of T (4 acc regs = 4 consecutive packed
        // elems: chunk = rowBase/8 + quad/2, k&7 = (quad&1)*4 + r).
        const long chunk = (rowBase >> 3) + (quad >> 1);
        const int  swz   = (int)((chunk & 3) << 4);
        char* tb = (char*)TTp + chunk * 2048 + (quad & 1) * 8;
        bf16x4 p0, p1;
#pragma unroll
        for (int r = 0; r < 4; ++r) {
            p0[r] = (__bf16)acc0[r];
            p1[r] = (__bf16)acc1[r];
        }
        *(bf16x4*)(tb + (((2 * w) * 256 + lo * 16) ^ swz))     = p0;
        *(bf16x4*)(tb + (((2 * w + 1) * 256 + lo * 16) ^ swz)) = p1;
    } else {
        // Fused row L2-normalize via LDS overlay (all staging drained).
        __syncthreads();
        float (*Cs)[136] = (float (*)[136])lds;
#pragma unroll
        for (int r = 0; r < 4; ++r) {
            Cs[quad * 4 + r][(2 * w) * 16 + lo]     = acc0[r];
            Cs[quad * 4 + r][(2 * w + 1) * 16 + lo] = acc1[r];
        }
        __syncthreads();
        const int row = tid >> 4;
        const int cg  = tid & 15;
        const f32x4 c0 = *(const f32x4*)&Cs[row][cg * 8];
        const f32x4 c1 = *(const f32x4*)&Cs[row][cg * 8 + 4];
        float sq = c0[0] * c0[0] + c0[1] * c0[1] + c0[2] * c0[2] +
                   c0[3] * c0[3] + c1[0] * c1[0] + c1[1] * c1[1] +
                   c1[2] * c1[2] + c1[3] * c1[3];
#pragma unroll
        for (int m = 1; m < 16; m <<= 1) sq += __shfl_xor(sq, m, 64);
        const float s = rsqrtf(sq);
        float* op = out + (size_t)(rowBase + row) * HIDDEN + cg * 8;
        f32x4 o0, o1;
#pragma unroll
        for (int j = 0; j < 4; ++j) { o0[j] = c0[j] * s; o1[j] = c1[j] * s; }
        *(f32x4*)(op)     = o0;
        *(f32x4*)(op + 4) = o1;
    }
}

// ---------------------------------------------------------------------------
// out = normalize_rows( D @ (A @ E) )
// 3 dispatches: gather -> gemm<1> (packed T) -> gemm<2> (fused normalize).
// ws: ETp 1MB | TTp 1MB.
// ---------------------------------------------------------------------------
extern "C" void kernel_launch(void* const* d_in, const int* in_sizes, int n_in,
                              void* d_out, int out_size, void* d_ws, size_t ws_size,
                              hipStream_t stream) {
    const float* emb   = (const float*)d_in[0];
    const int*   items = (const int*)d_in[1];
    const float* A     = (const float*)d_in[2];
    const float* D     = (const float*)d_in[3];
    float* out = (float*)d_out;

    __bf16* ETp = (__bf16*)d_ws;
    __bf16* TTp = ETp + NB;

    gather_sum_kernel<<<BATCH / 4, 256, 0, stream>>>(emb, items, ETp);
    gemm_mfma_kernel<1><<<BATCH / 16, 256, 0, stream>>>(A, ETp, TTp, nullptr);
    gemm_mfma_kernel<2><<<BATCH / 16, 256, 0, stream>>>(D, TTp, nullptr, out);
}